// Round 1
// 2642.948 us; speedup vs baseline: 1.3123x; 1.3123x over previous
//
#include <hip/hip_runtime.h>
#include <math.h>

#define B 8192
#define T 20
#define NF 812
#define HID 400
#define NG 1600          // 4*HID
#define NGP 1664         // padded N (13*128)
#define VARI 811
#define KP 832           // padded K for pre GEMM (813 used, rest 0)
#define KPB (KP * 2)     // bytes per row
#define KPC 13           // KP/64
#define KH 448           // padded K for h GEMM (400 used, rest 0)
#define KHB (KH * 2)
#define KHC 7            // KH/64
#define BM 128
#define BN 128
#define MROWS (B * T)    // 163840
#define PRE_BLOCKS (13 * (MROWS / BM))   // 16640
#define STEP_BLOCKS (13 * (B / BM))      // 832
#define GT_STRIDE 68     // floats; 272B row => float4-aligned, 2-way banks

typedef __attribute__((ext_vector_type(8))) short short8;
typedef __attribute__((ext_vector_type(4))) short short4v;
typedef __attribute__((ext_vector_type(4))) unsigned short ushort4v;
typedef __attribute__((ext_vector_type(4))) float floatx4;

__device__ inline short f2bf(float f) {
    union { float f; unsigned u; } v; v.f = f;
    unsigned r = v.u + 0x7FFF + ((v.u >> 16) & 1);
    return (short)(r >> 16);
}
__device__ inline float bf2f(unsigned short s) {
    union { float f; unsigned u; } v; v.u = ((unsigned)s) << 16;
    return v.f;
}
__device__ inline void glds16(const void* g, void* l) {
    __builtin_amdgcn_global_load_lds(
        (const __attribute__((address_space(1))) void*)g,
        (__attribute__((address_space(3))) void*)l, 16, 0, 0);
}
__device__ inline float sigm(float x) { return 1.f / (1.f + expf(-x)); }

// ---------------------------------------------------------------------------
// Shared 128x128xBK64 mainloop.  4 waves, wave tile 64x64, acc[4][4].
// LDS rows are 128B (8 x 16B slots); slot rotation (s+row)&7 kills the
// 8/16-way bank conflicts; the inverse rotation is applied to the GLOBAL
// source address so global_load_lds' linear lane->LDS mapping stays valid.
// A and B must share the same row stride in bytes (kbytes_row).
// ---------------------------------------------------------------------------
__device__ inline void gemm_mainloop(const char* __restrict__ Ag,
                                     const char* __restrict__ Bg,
                                     short* As, short* Bs,
                                     int kc_count, int kbytes_row,
                                     int wave, int lane,
                                     floatx4 acc[4][4]) {
    int wm = wave & 1, wn = wave >> 1;
    int q = lane >> 4;        // 16B slot group within K=32
    int mr = lane & 15;       // fragment row
    int rsub = lane >> 3;     // 0..7: row within 8-row staging chunk
    int cix = ((lane & 7) - rsub) & 7;   // inverse slot rotation for store

    for (int kc = 0; kc < kc_count; kc++) {
        int kbyte = kc * 128;
#pragma unroll
        for (int i = 0; i < 4; i++) {
            int r0 = wave * 32 + i * 8;          // wave-uniform chunk base
            int r = r0 + rsub;
            glds16(Ag + (size_t)r * kbytes_row + kbyte + cix * 16,
                   (char*)As + r0 * 128);
            glds16(Bg + (size_t)r * kbytes_row + kbyte + cix * 16,
                   (char*)Bs + r0 * 128);
        }
        __syncthreads();
        const short8* Av = (const short8*)As;
        const short8* Bv = (const short8*)Bs;
#pragma unroll
        for (int kk = 0; kk < 2; kk++) {
            short8 a[4], b[4];
#pragma unroll
            for (int f = 0; f < 4; f++) {
                int arow = wm * 64 + f * 16 + mr;
                a[f] = Av[arow * 8 + ((kk * 4 + q + mr) & 7)];
                int brow = wn * 64 + f * 16 + mr;
                b[f] = Bv[brow * 8 + ((kk * 4 + q + mr) & 7)];
            }
#pragma unroll
            for (int f = 0; f < 4; f++)
#pragma unroll
                for (int g = 0; g < 4; g++)
                    acc[f][g] = __builtin_amdgcn_mfma_f32_16x16x32_bf16(
                        a[f], b[g], acc[f][g], 0, 0, 0);
        }
        __syncthreads();
    }
}

// ---------------------------------------------------------------------------
// prep: wsum[j] = sum_k W_decay[j][k] ; den[t] = sum_b masks[b][t]
// ---------------------------------------------------------------------------
__global__ void prep_kernel(const float* __restrict__ W_decay,
                            const float* __restrict__ masks,
                            float* __restrict__ wsum,
                            float* __restrict__ den) {
    int blk = blockIdx.x;
    int lane = threadIdx.x;
    if (blk < HID) {
        float s = 0.f;
        for (int k = lane; k < NF; k += 64) s += W_decay[blk * NF + k];
        for (int o = 32; o; o >>= 1) s += __shfl_down(s, o);
        if (lane == 0) wsum[blk] = s;
    } else {
        int t = blk - HID;
        if (t < T) {
            float s = 0.f;
            for (int b = lane; b < B; b += 64) s += masks[b * T + t];
            for (int o = 32; o; o >>= 1) s += __shfl_down(s, o);
            if (lane == 0) den[t] = s;
        }
    }
}

// ---------------------------------------------------------------------------
// conv_inp: Inp_bf16[row][k], row = b*T+t, k<811: values, 811: 0, 812: mask,
// 813..831: 0.  One block per row; thread t handles cols 4t..4t+3 (t<208).
// ---------------------------------------------------------------------------
__global__ void conv_inp(const float* __restrict__ values,
                         const float* __restrict__ masks,
                         short* __restrict__ Inpb) {
    int row = blockIdx.x;
    int t = threadIdx.x;
    if (t >= 208) return;
    short4v o;
    if (t < 202) {
        const float4* src = (const float4*)(values + (size_t)row * NF + 4 * t);
        float4 v = *src;
        o.x = f2bf(v.x); o.y = f2bf(v.y); o.z = f2bf(v.z); o.w = f2bf(v.w);
    } else if (t == 202) {  // cols 808..811 ; 811 -> 0
        const float4* src = (const float4*)(values + (size_t)row * NF + 808);
        float4 v = *src;
        o.x = f2bf(v.x); o.y = f2bf(v.y); o.z = f2bf(v.z); o.w = 0;
    } else if (t == 203) {  // cols 812..815 : mask,0,0,0
        o.x = f2bf(masks[row]); o.y = 0; o.z = 0; o.w = 0;
    } else {
        o.x = o.y = o.z = o.w = 0;
    }
    *(short4v*)(Inpb + (size_t)row * KP + 4 * t) = o;
}

// ---------------------------------------------------------------------------
// conv_wih: reorder W_ih rows r'=j*4+g <- r=g*400+j, pad K to 832, pad rows
// to NGP with zeros, bf16.  w811r[r'] = W_ih[r][811], biasr[r'] = b_ih+b_hh.
// ---------------------------------------------------------------------------
__global__ void conv_wih(const float* __restrict__ W_ih,
                         const float* __restrict__ b_ih,
                         const float* __restrict__ b_hh,
                         short* __restrict__ Wihb,
                         float* __restrict__ w811r,
                         float* __restrict__ biasr) {
    int rp = blockIdx.x;          // 0..NGP-1
    int t = threadIdx.x;
    if (rp < NG) {
        int j = rp >> 2, g = rp & 3;
        int r = g * HID + j;
        if (t < 208) {
            short4v o;
#pragma unroll
            for (int i = 0; i < 4; i++) {
                int k = 4 * t + i;
                float v = (k < NF + 1) ? W_ih[(size_t)r * (NF + 1) + k] : 0.f;
                ((short*)&o)[i] = f2bf(v);
            }
            *(short4v*)(Wihb + (size_t)rp * KP + 4 * t) = o;
        } else if (t == 255) {
            w811r[rp] = W_ih[(size_t)r * (NF + 1) + VARI];
            biasr[rp] = b_ih[r] + b_hh[r];
        }
    } else {
        if (t < 208) {
            short4v o; o.x = o.y = o.z = o.w = 0;
            *(short4v*)(Wihb + (size_t)rp * KP + 4 * t) = o;
        } else if (t == 255) {
            w811r[rp] = 0.f;
            biasr[rp] = 0.f;
        }
    }
}

// conv_whh: reorder W_hh rows, pad K 400->448, pad rows to NGP, bf16.
__global__ void conv_whh(const float* __restrict__ W_hh,
                         short* __restrict__ Whhb) {
    int rp = blockIdx.x;
    int t = threadIdx.x;
    if (t >= 112) return;         // 448/4
    short4v o; o.x = o.y = o.z = o.w = 0;
    if (rp < NG) {
        int j = rp >> 2, g = rp & 3;
        int r = g * HID + j;
#pragma unroll
        for (int i = 0; i < 4; i++) {
            int k = 4 * t + i;
            float v = (k < HID) ? W_hh[(size_t)r * HID + k] : 0.f;
            ((short*)&o)[i] = f2bf(v);
        }
    }
    *(short4v*)(Whhb + (size_t)rp * KH + 4 * t) = o;
}

// ---------------------------------------------------------------------------
// pre_gemm: pre[row][n] = Inp[row][:] . Wihb[n][:] + biasr[n]   (bf16 out)
// M=163840, N=1664(pad), K=832.  128x128 tile; XCD-chunked block swizzle so
// the 13 N-tiles sharing an A slab run on the same XCD (L2 reuse).
// ---------------------------------------------------------------------------
__global__ __launch_bounds__(256, 2)
void pre_gemm(const short* __restrict__ Inpb,
              const short* __restrict__ Wihb,
              const float* __restrict__ biasr,
              short* __restrict__ preb) {
    __shared__ __align__(16) short As[BM * 64];
    __shared__ __align__(16) short Bs[BN * 64];
    int lin = blockIdx.x;
    int swz = (lin & 7) * (PRE_BLOCKS / 8) + (lin >> 3);
    int ty = swz / 13, tx = swz - ty * 13;
    int row0 = ty * BM, n0 = tx * BN;
    int tid = threadIdx.x, lane = tid & 63, wave = tid >> 6;

    floatx4 acc[4][4] = {};
    gemm_mainloop((const char*)(Inpb + (size_t)row0 * KP),
                  (const char*)(Wihb + (size_t)n0 * KP),
                  As, Bs, KPC, KPB, wave, lane, acc);

    int wm = wave & 1, wn = wave >> 1, q = lane >> 4, mr = lane & 15;
#pragma unroll
    for (int g = 0; g < 4; g++) {
        int gn = n0 + wn * 64 + g * 16 + mr;
        if (gn < NG) {
            float bia = biasr[gn];
#pragma unroll
            for (int f = 0; f < 4; f++)
#pragma unroll
                for (int r = 0; r < 4; r++) {
                    int m = wm * 64 + f * 16 + q * 4 + r;
                    preb[(size_t)(row0 + m) * NG + gn] = f2bf(acc[f][g][r] + bia);
                }
        }
    }
}

// ---------------------------------------------------------------------------
// decay + imputation.  One wave per 2 rows (8192 waves = 32/CU), no h
// writeback (decayed h only feeds hbf; next-step h comes from step_gemm).
// ---------------------------------------------------------------------------
__global__ __launch_bounds__(256)
void decay_impute(int t,
                  const float* __restrict__ values,
                  const float* __restrict__ masks,
                  const float* __restrict__ deltas,
                  const float* __restrict__ b_decay,
                  const float* __restrict__ W_reg,
                  const float* __restrict__ b_reg,
                  const float* __restrict__ wsum,
                  const float* __restrict__ h,
                  short* __restrict__ hbf,
                  float* __restrict__ xvar,
                  float* __restrict__ num,
                  float* __restrict__ out_imp) {
    __shared__ float red[4];
    int wave = threadIdx.x >> 6;
    int lane = threadIdx.x & 63;
    float lnum = 0.f;
#pragma unroll
    for (int i = 0; i < 2; i++) {
        int b = (blockIdx.x * 4 + wave) * 2 + i;
        float d = deltas[b * T + t];
        float m = masks[b * T + t];
        float dot = 0.f;
        for (int j = lane; j < HID; j += 64) {
            float g = expf(-fmaxf(fmaf(d, wsum[j], b_decay[j]), 0.f));
            float hv = h[(size_t)b * HID + j] * g;
            hbf[(size_t)b * KH + j] = f2bf(hv);
            dot = fmaf(hv, W_reg[j], dot);
        }
        if (lane < KH - HID) hbf[(size_t)b * KH + HID + lane] = 0;
        for (int o = 32; o; o >>= 1) dot += __shfl_down(dot, o);
        if (lane == 0) {
            float x_h = dot + b_reg[0];
            float xv = values[(size_t)(b * T + t) * NF + VARI];
            float x_var = xv * m + (1.f - m) * x_h;
            out_imp[b * T + t] = x_var;
            xvar[b] = x_var;
            if (m != 0.f) lnum += fabsf(x_var - x_h);
        }
    }
    if (lane == 0) red[wave] = lnum;
    __syncthreads();
    if (threadIdx.x == 0)
        atomicAdd(&num[t], red[0] + red[1] + red[2] + red[3]);
}

// ---------------------------------------------------------------------------
// step_gemm: gates = hbf @ Whhb^T (128x128 tile); epilogue adds pre +
// xvar*w811, applies LSTM cell.  Epilogue transposes acc through LDS in two
// 64-col halves (gt reuses the As/Bs space).
// ---------------------------------------------------------------------------
__global__ __launch_bounds__(256, 2)
void step_gemm(int t,
               const short* __restrict__ hbf,
               const short* __restrict__ Whhb,
               const short* __restrict__ preb,
               const float* __restrict__ w811r,
               const float* __restrict__ xvar,
               float* __restrict__ c,
               float* __restrict__ h_out) {
    __shared__ __align__(16) char smem[BM * GT_STRIDE * 4];  // 34816 B
    short* As = (short*)smem;
    short* Bs = (short*)(smem + 16384);
    float* gt = (float*)smem;
    int lin = blockIdx.x;
    int swz = (lin & 7) * (STEP_BLOCKS / 8) + (lin >> 3);
    int ty = swz / 13, tx = swz - ty * 13;
    int b0 = ty * BM, n0 = tx * BN;
    int tid = threadIdx.x, lane = tid & 63, wave = tid >> 6;

    floatx4 acc[4][4] = {};
    gemm_mainloop((const char*)(hbf + (size_t)b0 * KH),
                  (const char*)(Whhb + (size_t)n0 * KH),
                  As, Bs, KHC, KHB, wave, lane, acc);

    int wm = wave & 1, wn = wave >> 1, q = lane >> 4, mr = lane & 15;
    int jl = tid & 15, bb0 = tid >> 4;
#pragma unroll
    for (int nh = 0; nh < 2; nh++) {
        __syncthreads();
        if (wn == nh) {
#pragma unroll
            for (int f = 0; f < 4; f++)
#pragma unroll
                for (int g = 0; g < 4; g++)
#pragma unroll
                    for (int r = 0; r < 4; r++)
                        gt[(wm * 64 + f * 16 + q * 4 + r) * GT_STRIDE +
                           g * 16 + mr] = acc[f][g][r];
        }
        __syncthreads();
        int rpb = n0 + nh * 64 + jl * 4;   // reordered gate-row base
        int j = rpb >> 2;                  // hidden unit (0..415)
        float w0 = w811r[rpb + 0];
        float w1 = w811r[rpb + 1];
        float w2 = w811r[rpb + 2];
        float w3 = w811r[rpb + 3];
        bool inb = (rpb < NG);
        bool jok = (j < HID);
#pragma unroll
        for (int i = 0; i < 8; i++) {
            int bb = bb0 + i * 16;
            int b = b0 + bb;
            float xv = xvar[b];
            float4 gv = *(const float4*)&gt[bb * GT_STRIDE + jl * 4];
            float pi = 0.f, pf = 0.f, pg = 0.f, po = 0.f;
            if (inb) {
                ushort4v pv = *(const ushort4v*)(preb +
                    ((size_t)b * T + t) * NG + rpb);
                pi = bf2f(pv.x); pf = bf2f(pv.y);
                pg = bf2f(pv.z); po = bf2f(pv.w);
            }
            float gi = gv.x + pi + xv * w0;
            float gf = gv.y + pf + xv * w1;
            float gg = gv.z + pg + xv * w2;
            float go = gv.w + po + xv * w3;
            if (jok) {
                size_t idx = (size_t)b * HID + j;
                float cn = sigm(gf) * c[idx] + sigm(gi) * tanhf(gg);
                c[idx] = cn;
                h_out[idx] = sigm(go) * tanhf(cn);
            }
        }
    }
}

__global__ void finalize_kernel(const float* __restrict__ num,
                                const float* __restrict__ den,
                                float* __restrict__ out) {
    if (threadIdx.x == 0) {
        float s = 0.f;
        for (int t = 0; t < T; t++) s += num[t] / (den[t] + 1e-5f);
        out[0] = s / (float)T;
    }
}

extern "C" void kernel_launch(void* const* d_in, const int* in_sizes, int n_in,
                              void* d_out, int out_size, void* d_ws, size_t ws_size,
                              hipStream_t stream) {
    const float* values  = (const float*)d_in[0];
    const float* masks   = (const float*)d_in[1];
    const float* deltas  = (const float*)d_in[2];
    const float* W_decay = (const float*)d_in[3];
    const float* b_decay = (const float*)d_in[4];
    const float* W_reg   = (const float*)d_in[5];
    const float* b_reg   = (const float*)d_in[6];
    const float* W_ih    = (const float*)d_in[7];
    const float* W_hh    = (const float*)d_in[8];
    const float* b_ih    = (const float*)d_in[9];
    const float* b_hh    = (const float*)d_in[10];
    float* out = (float*)d_out;

    char* p = (char*)d_ws;
    auto alloc = [&](size_t bytes) { char* r = p; p += (bytes + 255) & ~(size_t)255; return r; };
    const size_t BH = (size_t)B * HID;
    float* h0    = (float*)alloc(BH * 4);
    float* c     = (float*)alloc(BH * 4);          // contiguous with h0
    float* h1    = (float*)alloc(BH * 4);
    short* hbf   = (short*)alloc((size_t)B * KH * 2);
    float* xvar  = (float*)alloc(B * 4);
    float* wsum  = (float*)alloc(HID * 4);
    float* w811r = (float*)alloc(NGP * 4);
    float* biasr = (float*)alloc(NGP * 4);
    float* num   = (float*)alloc(32 * 4);
    float* den   = (float*)alloc(32 * 4);
    short* Wihb  = (short*)alloc((size_t)NGP * KP * 2);
    short* Whhb  = (short*)alloc((size_t)NGP * KH * 2);
    short* Inpb  = (short*)alloc((size_t)MROWS * KP * 2);
    short* preb  = (short*)alloc((size_t)MROWS * NG * 2);

    hipMemsetAsync(h0, 0, 2 * BH * 4, stream);   // h0 + c
    hipMemsetAsync(num, 0, 32 * 4, stream);

    prep_kernel<<<HID + T, 64, 0, stream>>>(W_decay, masks, wsum, den);
    conv_wih<<<NGP, 256, 0, stream>>>(W_ih, b_ih, b_hh, Wihb, w811r, biasr);
    conv_whh<<<NGP, 128, 0, stream>>>(W_hh, Whhb);
    conv_inp<<<MROWS, 256, 0, stream>>>(values, masks, Inpb);
    pre_gemm<<<PRE_BLOCKS, 256, 0, stream>>>(Inpb, Wihb, biasr, preb);
    for (int t = 0; t < T; t++) {
        float* hin  = (t & 1) ? h1 : h0;
        float* hout = (t & 1) ? h0 : h1;
        decay_impute<<<B / 8, 256, 0, stream>>>(
            t, values, masks, deltas, b_decay, W_reg, b_reg, wsum,
            hin, hbf, xvar, num, out + 1);
        step_gemm<<<STEP_BLOCKS, 256, 0, stream>>>(
            t, hbf, Whhb, preb, w811r, xvar, c, hout);
    }
    finalize_kernel<<<1, 64, 0, stream>>>(num, den, out);
}

// Round 2
// 2376.083 us; speedup vs baseline: 1.4597x; 1.1123x over previous
//
#include <hip/hip_runtime.h>
#include <math.h>

#define B 8192
#define T 20
#define NF 812
#define HID 400
#define NG 1600          // 4*HID
#define NGP 1664         // padded N (13*128)
#define VARI 811
#define KP 832           // padded K for pre GEMM (813 used, rest 0)
#define KPB (KP * 2)     // bytes per row
#define KPC 13           // KP/64
#define KH 448           // padded K for h GEMM (400 used, rest 0)
#define KHB (KH * 2)
#define KHC 7            // KH/64
#define BM 128
#define BN 128
#define MROWS (B * T)    // 163840
#define PRE_BLOCKS (13 * (MROWS / BM))   // 16640
#define STEP_BLOCKS (13 * (B / BM))      // 832
#define GT_STRIDE 68     // floats; 272B row => float4-aligned, 2-way banks

typedef __attribute__((ext_vector_type(8))) short short8;
typedef __attribute__((ext_vector_type(4))) short short4v;
typedef __attribute__((ext_vector_type(4))) unsigned short ushort4v;
typedef __attribute__((ext_vector_type(4))) float floatx4;

__device__ inline short f2bf(float f) {
    union { float f; unsigned u; } v; v.f = f;
    unsigned r = v.u + 0x7FFF + ((v.u >> 16) & 1);
    return (short)(r >> 16);
}
__device__ inline float bf2f(unsigned short s) {
    union { float f; unsigned u; } v; v.u = ((unsigned)s) << 16;
    return v.f;
}
__device__ inline void glds16(const void* g, void* l) {
    __builtin_amdgcn_global_load_lds(
        (const __attribute__((address_space(1))) void*)g,
        (__attribute__((address_space(3))) void*)l, 16, 0, 0);
}
__device__ inline float sigm(float x) { return 1.f / (1.f + expf(-x)); }

// ---------------------------------------------------------------------------
// Shared 128x128xBK64 mainloop.  4 waves, wave tile 64x64, acc[4][4].
// LDS rows are 128B (8 x 16B slots); slot rotation (s+row)&7 kills the
// 8/16-way bank conflicts; the inverse rotation is applied to the GLOBAL
// source address so global_load_lds' linear lane->LDS mapping stays valid.
// ---------------------------------------------------------------------------
__device__ inline void gemm_mainloop(const char* __restrict__ Ag,
                                     const char* __restrict__ Bg,
                                     short* As, short* Bs,
                                     int kc_count, int kbytes_row,
                                     int wave, int lane,
                                     floatx4 acc[4][4]) {
    int wm = wave & 1, wn = wave >> 1;
    int q = lane >> 4;        // 16B slot group within K=32
    int mr = lane & 15;       // fragment row
    int rsub = lane >> 3;     // 0..7: row within 8-row staging chunk
    int cix = ((lane & 7) - rsub) & 7;   // inverse slot rotation for store

    for (int kc = 0; kc < kc_count; kc++) {
        int kbyte = kc * 128;
#pragma unroll
        for (int i = 0; i < 4; i++) {
            int r0 = wave * 32 + i * 8;          // wave-uniform chunk base
            int r = r0 + rsub;
            glds16(Ag + (size_t)r * kbytes_row + kbyte + cix * 16,
                   (char*)As + r0 * 128);
            glds16(Bg + (size_t)r * kbytes_row + kbyte + cix * 16,
                   (char*)Bs + r0 * 128);
        }
        __syncthreads();
        const short8* Av = (const short8*)As;
        const short8* Bv = (const short8*)Bs;
#pragma unroll
        for (int kk = 0; kk < 2; kk++) {
            short8 a[4], b[4];
#pragma unroll
            for (int f = 0; f < 4; f++) {
                int arow = wm * 64 + f * 16 + mr;
                a[f] = Av[arow * 8 + ((kk * 4 + q + mr) & 7)];
                int brow = wn * 64 + f * 16 + mr;
                b[f] = Bv[brow * 8 + ((kk * 4 + q + mr) & 7)];
            }
#pragma unroll
            for (int f = 0; f < 4; f++)
#pragma unroll
                for (int g = 0; g < 4; g++)
                    acc[f][g] = __builtin_amdgcn_mfma_f32_16x16x32_bf16(
                        a[f], b[g], acc[f][g], 0, 0, 0);
        }
        __syncthreads();
    }
}

// ---------------------------------------------------------------------------
// prep: wsum[j] = sum_k W_decay[j][k] ; den[t] = sum_b masks[b][t]
// ---------------------------------------------------------------------------
__global__ void prep_kernel(const float* __restrict__ W_decay,
                            const float* __restrict__ masks,
                            float* __restrict__ wsum,
                            float* __restrict__ den) {
    int blk = blockIdx.x;
    int lane = threadIdx.x;
    if (blk < HID) {
        float s = 0.f;
        for (int k = lane; k < NF; k += 64) s += W_decay[blk * NF + k];
        for (int o = 32; o; o >>= 1) s += __shfl_down(s, o);
        if (lane == 0) wsum[blk] = s;
    } else {
        int t = blk - HID;
        if (t < T) {
            float s = 0.f;
            for (int b = lane; b < B; b += 64) s += masks[b * T + t];
            for (int o = 32; o; o >>= 1) s += __shfl_down(s, o);
            if (lane == 0) den[t] = s;
        }
    }
}

// ---------------------------------------------------------------------------
// conv_inp: Inp_bf16[row][k], row = b*T+t, k<811: values, 811: 0, 812: mask,
// 813..831: 0.
// ---------------------------------------------------------------------------
__global__ void conv_inp(const float* __restrict__ values,
                         const float* __restrict__ masks,
                         short* __restrict__ Inpb) {
    int row = blockIdx.x;
    int t = threadIdx.x;
    if (t >= 208) return;
    short4v o;
    if (t < 202) {
        const float4* src = (const float4*)(values + (size_t)row * NF + 4 * t);
        float4 v = *src;
        o.x = f2bf(v.x); o.y = f2bf(v.y); o.z = f2bf(v.z); o.w = f2bf(v.w);
    } else if (t == 202) {  // cols 808..811 ; 811 -> 0
        const float4* src = (const float4*)(values + (size_t)row * NF + 808);
        float4 v = *src;
        o.x = f2bf(v.x); o.y = f2bf(v.y); o.z = f2bf(v.z); o.w = 0;
    } else if (t == 203) {  // cols 812..815 : mask,0,0,0
        o.x = f2bf(masks[row]); o.y = 0; o.z = 0; o.w = 0;
    } else {
        o.x = o.y = o.z = o.w = 0;
    }
    *(short4v*)(Inpb + (size_t)row * KP + 4 * t) = o;
}

// ---------------------------------------------------------------------------
// conv_wih: reorder W_ih rows r'=j*4+g <- r=g*400+j, pad K to 832, pad rows
// to NGP with zeros, bf16.  w811r[r'] = W_ih[r][811], biasr[r'] = b_ih+b_hh.
// ---------------------------------------------------------------------------
__global__ void conv_wih(const float* __restrict__ W_ih,
                         const float* __restrict__ b_ih,
                         const float* __restrict__ b_hh,
                         short* __restrict__ Wihb,
                         float* __restrict__ w811r,
                         float* __restrict__ biasr) {
    int rp = blockIdx.x;          // 0..NGP-1
    int t = threadIdx.x;
    if (rp < NG) {
        int j = rp >> 2, g = rp & 3;
        int r = g * HID + j;
        if (t < 208) {
            short4v o;
#pragma unroll
            for (int i = 0; i < 4; i++) {
                int k = 4 * t + i;
                float v = (k < NF + 1) ? W_ih[(size_t)r * (NF + 1) + k] : 0.f;
                ((short*)&o)[i] = f2bf(v);
            }
            *(short4v*)(Wihb + (size_t)rp * KP + 4 * t) = o;
        } else if (t == 255) {
            w811r[rp] = W_ih[(size_t)r * (NF + 1) + VARI];
            biasr[rp] = b_ih[r] + b_hh[r];
        }
    } else {
        if (t < 208) {
            short4v o; o.x = o.y = o.z = o.w = 0;
            *(short4v*)(Wihb + (size_t)rp * KP + 4 * t) = o;
        } else if (t == 255) {
            w811r[rp] = 0.f;
            biasr[rp] = 0.f;
        }
    }
}

// conv_whh: reorder W_hh rows, pad K 400->448, pad rows to NGP, bf16.
__global__ void conv_whh(const float* __restrict__ W_hh,
                         short* __restrict__ Whhb) {
    int rp = blockIdx.x;
    int t = threadIdx.x;
    if (t >= 112) return;         // 448/4
    short4v o; o.x = o.y = o.z = o.w = 0;
    if (rp < NG) {
        int j = rp >> 2, g = rp & 3;
        int r = g * HID + j;
#pragma unroll
        for (int i = 0; i < 4; i++) {
            int k = 4 * t + i;
            float v = (k < HID) ? W_hh[(size_t)r * HID + k] : 0.f;
            ((short*)&o)[i] = f2bf(v);
        }
    }
    *(short4v*)(Whhb + (size_t)rp * KH + 4 * t) = o;
}

// ---------------------------------------------------------------------------
// pre_gemm: pre[row][n] = Inp[row][:] . Wihb[n][:] + biasr[n]   (bf16 out)
// ---------------------------------------------------------------------------
__global__ __launch_bounds__(256, 2)
void pre_gemm(const short* __restrict__ Inpb,
              const short* __restrict__ Wihb,
              const float* __restrict__ biasr,
              short* __restrict__ preb) {
    __shared__ __align__(16) short As[BM * 64];
    __shared__ __align__(16) short Bs[BN * 64];
    int lin = blockIdx.x;
    int swz = (lin & 7) * (PRE_BLOCKS / 8) + (lin >> 3);
    int ty = swz / 13, tx = swz - ty * 13;
    int row0 = ty * BM, n0 = tx * BN;
    int tid = threadIdx.x, lane = tid & 63, wave = tid >> 6;

    floatx4 acc[4][4] = {};
    gemm_mainloop((const char*)(Inpb + (size_t)row0 * KP),
                  (const char*)(Wihb + (size_t)n0 * KP),
                  As, Bs, KPC, KPB, wave, lane, acc);

    int wm = wave & 1, wn = wave >> 1, q = lane >> 4, mr = lane & 15;
#pragma unroll
    for (int g = 0; g < 4; g++) {
        int gn = n0 + wn * 64 + g * 16 + mr;
        if (gn < NG) {
            float bia = biasr[gn];
#pragma unroll
            for (int f = 0; f < 4; f++)
#pragma unroll
                for (int r = 0; r < 4; r++) {
                    int m = wm * 64 + f * 16 + q * 4 + r;
                    preb[(size_t)(row0 + m) * NG + gn] = f2bf(acc[f][g][r] + bia);
                }
        }
    }
}

// ---------------------------------------------------------------------------
// xvar_kernel(t): turn accumulated xh partials into x_var / loss numerator.
// Runs BEFORE step_gemm(t).  Zeroes its xh buffer for reuse at t+2.
// ---------------------------------------------------------------------------
__global__ __launch_bounds__(256)
void xvar_kernel(int t,
                 const float* __restrict__ values,
                 const float* __restrict__ masks,
                 const float* __restrict__ b_reg,
                 float* __restrict__ xh,       // buffer (t&1)
                 float* __restrict__ xvar,
                 float* __restrict__ num,
                 float* __restrict__ out_imp) {
    __shared__ float red[4];
    int b = blockIdx.x * 256 + threadIdx.x;
    float x_h = xh[b] + b_reg[0];
    xh[b] = 0.f;                                // reset for step t+2
    float m = masks[b * T + t];
    float xv = values[(size_t)(b * T + t) * NF + VARI];
    float x_var = xv * m + (1.f - m) * x_h;
    out_imp[b * T + t] = x_var;
    xvar[b] = x_var;
    float l = (m != 0.f) ? fabsf(x_var - x_h) : 0.f;
    for (int o = 32; o; o >>= 1) l += __shfl_down(l, o);
    int lane = threadIdx.x & 63, wave = threadIdx.x >> 6;
    if (lane == 0) red[wave] = l;
    __syncthreads();
    if (threadIdx.x == 0)
        atomicAdd(&num[t], red[0] + red[1] + red[2] + red[3]);
}

// ---------------------------------------------------------------------------
// step_gemm: gates = hbf_in @ Whhb^T; epilogue adds pre + xvar*w811, applies
// LSTM cell, then FUSES the t+1 decay: hv = h_new * gamma(t+1), written
// straight to hbf_out (bf16, double-buffered vs hbf_in to avoid the
// cross-block read/write race).  x_h partials accumulated into xh_next via
// 16-lane shfl reduce + one atomicAdd per (b, block).
// ---------------------------------------------------------------------------
__global__ __launch_bounds__(256, 2)
void step_gemm(int t,
               const short* __restrict__ hbf_in,
               short* __restrict__ hbf_out,
               const short* __restrict__ Whhb,
               const short* __restrict__ preb,
               const float* __restrict__ w811r,
               const float* __restrict__ xvar,
               const float* __restrict__ deltas,
               const float* __restrict__ b_decay,
               const float* __restrict__ wsum,
               const float* __restrict__ W_reg,
               float* __restrict__ c,
               float* __restrict__ xh_next) {
    __shared__ __align__(16) char smem[BM * GT_STRIDE * 4];  // 34816 B
    short* As = (short*)smem;
    short* Bs = (short*)(smem + 16384);
    float* gt = (float*)smem;
    int lin = blockIdx.x;
    int swz = (lin & 7) * (STEP_BLOCKS / 8) + (lin >> 3);
    int ty = swz / 13, tx = swz - ty * 13;
    int b0 = ty * BM, n0 = tx * BN;
    int tid = threadIdx.x, lane = tid & 63, wave = tid >> 6;

    floatx4 acc[4][4] = {};
    gemm_mainloop((const char*)(hbf_in + (size_t)b0 * KH),
                  (const char*)(Whhb + (size_t)n0 * KH),
                  As, Bs, KHC, KHB, wave, lane, acc);

    int wm = wave & 1, wn = wave >> 1, q = lane >> 4, mr = lane & 15;
    int jl = tid & 15, bb0 = tid >> 4;
    bool dec = (t + 1 < T);
    float xhp[8];
#pragma unroll
    for (int i = 0; i < 8; i++) xhp[i] = 0.f;

#pragma unroll
    for (int nh = 0; nh < 2; nh++) {
        __syncthreads();
        if (wn == nh) {
#pragma unroll
            for (int f = 0; f < 4; f++)
#pragma unroll
                for (int g = 0; g < 4; g++)
#pragma unroll
                    for (int r = 0; r < 4; r++)
                        gt[(wm * 64 + f * 16 + q * 4 + r) * GT_STRIDE +
                           g * 16 + mr] = acc[f][g][r];
        }
        __syncthreads();
        int rpb = n0 + nh * 64 + jl * 4;   // reordered gate-row base
        int j = rpb >> 2;                  // hidden unit (0..415)
        float w0 = w811r[rpb + 0];
        float w1 = w811r[rpb + 1];
        float w2 = w811r[rpb + 2];
        float w3 = w811r[rpb + 3];
        bool inb = (rpb < NG);
        bool jok = (j < HID);
        float wsj = jok ? wsum[j] : 0.f;
        float bdj = jok ? b_decay[j] : 0.f;
        float wrj = jok ? W_reg[j] : 0.f;
#pragma unroll
        for (int i = 0; i < 8; i++) {
            int bb = bb0 + i * 16;
            int b = b0 + bb;
            float xv = xvar[b];
            float4 gv = *(const float4*)&gt[bb * GT_STRIDE + jl * 4];
            float pi = 0.f, pf = 0.f, pg = 0.f, po = 0.f;
            if (inb) {
                ushort4v pv = *(const ushort4v*)(preb +
                    ((size_t)b * T + t) * NG + rpb);
                pi = bf2f(pv.x); pf = bf2f(pv.y);
                pg = bf2f(pv.z); po = bf2f(pv.w);
            }
            float gi = gv.x + pi + xv * w0;
            float gf = gv.y + pf + xv * w1;
            float gg = gv.z + pg + xv * w2;
            float go = gv.w + po + xv * w3;
            if (jok) {
                size_t idx = (size_t)b * HID + j;
                float cn = sigm(gf) * c[idx] + sigm(gi) * tanhf(gg);
                c[idx] = cn;
                float hn = sigm(go) * tanhf(cn);
                if (dec) {
                    float d = deltas[b * T + t + 1];
                    float gam = expf(-fmaxf(fmaf(d, wsj, bdj), 0.f));
                    float hv = hn * gam;
                    hbf_out[(size_t)b * KH + j] = f2bf(hv);
                    xhp[i] += hv * wrj;
                }
            }
        }
    }
    if (dec) {
        // reduce xhp over the 16-lane jl group, then one atomic per (b,block)
#pragma unroll
        for (int i = 0; i < 8; i++) {
            float s = xhp[i];
            s += __shfl_xor(s, 1);
            s += __shfl_xor(s, 2);
            s += __shfl_xor(s, 4);
            s += __shfl_xor(s, 8);
            if (jl == 0) {
                int b = b0 + bb0 + i * 16;
                atomicAdd(&xh_next[b], s);
            }
        }
    }
}

__global__ void finalize_kernel(const float* __restrict__ num,
                                const float* __restrict__ den,
                                float* __restrict__ out) {
    if (threadIdx.x == 0) {
        float s = 0.f;
        for (int t = 0; t < T; t++) s += num[t] / (den[t] + 1e-5f);
        out[0] = s / (float)T;
    }
}

extern "C" void kernel_launch(void* const* d_in, const int* in_sizes, int n_in,
                              void* d_out, int out_size, void* d_ws, size_t ws_size,
                              hipStream_t stream) {
    const float* values  = (const float*)d_in[0];
    const float* masks   = (const float*)d_in[1];
    const float* deltas  = (const float*)d_in[2];
    const float* W_decay = (const float*)d_in[3];
    const float* b_decay = (const float*)d_in[4];
    const float* W_reg   = (const float*)d_in[5];
    const float* b_reg   = (const float*)d_in[6];
    const float* W_ih    = (const float*)d_in[7];
    const float* W_hh    = (const float*)d_in[8];
    const float* b_ih    = (const float*)d_in[9];
    const float* b_hh    = (const float*)d_in[10];
    float* out = (float*)d_out;

    char* p = (char*)d_ws;
    auto alloc = [&](size_t bytes) { char* r = p; p += (bytes + 255) & ~(size_t)255; return r; };
    const size_t BH = (size_t)B * HID;
    float* c     = (float*)alloc(BH * 4);
    short* hbf0  = (short*)alloc((size_t)B * KH * 2);
    short* hbf1  = (short*)alloc((size_t)B * KH * 2);
    float* xvar  = (float*)alloc(B * 4);
    float* xh0   = (float*)alloc(B * 4);       // contiguous with xh1
    float* xh1   = (float*)alloc(B * 4);
    float* wsum  = (float*)alloc(HID * 4);
    float* w811r = (float*)alloc(NGP * 4);
    float* biasr = (float*)alloc(NGP * 4);
    float* num   = (float*)alloc(32 * 4);
    float* den   = (float*)alloc(32 * 4);
    short* Wihb  = (short*)alloc((size_t)NGP * KP * 2);
    short* Whhb  = (short*)alloc((size_t)NGP * KH * 2);
    short* Inpb  = (short*)alloc((size_t)MROWS * KP * 2);
    short* preb  = (short*)alloc((size_t)MROWS * NG * 2);

    hipMemsetAsync(c, 0, BH * 4, stream);
    hipMemsetAsync(hbf0, 0, (size_t)B * KH * 2, stream);
    hipMemsetAsync(hbf1, 0, (size_t)B * KH * 2, stream);
    hipMemsetAsync(xh0, 0, (size_t)2 * B * 4, stream);   // xh0 + xh1
    hipMemsetAsync(num, 0, 32 * 4, stream);

    prep_kernel<<<HID + T, 64, 0, stream>>>(W_decay, masks, wsum, den);
    conv_wih<<<NGP, 256, 0, stream>>>(W_ih, b_ih, b_hh, Wihb, w811r, biasr);
    conv_whh<<<NGP, 128, 0, stream>>>(W_hh, Whhb);
    conv_inp<<<MROWS, 256, 0, stream>>>(values, masks, Inpb);
    pre_gemm<<<PRE_BLOCKS, 256, 0, stream>>>(Inpb, Wihb, biasr, preb);
    for (int t = 0; t < T; t++) {
        short* hin  = (t & 1) ? hbf1 : hbf0;
        short* hout = (t & 1) ? hbf0 : hbf1;
        float* xh_cur  = (t & 1) ? xh1 : xh0;
        float* xh_next = (t & 1) ? xh0 : xh1;
        xvar_kernel<<<B / 256, 256, 0, stream>>>(
            t, values, masks, b_reg, xh_cur, xvar, num, out + 1);
        step_gemm<<<STEP_BLOCKS, 256, 0, stream>>>(
            t, hin, hout, Whhb, preb, w811r, xvar,
            deltas, b_decay, wsum, W_reg, c, xh_next);
    }
    finalize_kernel<<<1, 64, 0, stream>>>(num, den, out);
}